// Round 2
// baseline (62.251 us; speedup 1.0000x reference)
//
#include <hip/hip_runtime.h>
#include <math.h>

// BatchAllTripletLoss, fully fused.
// batch = concat(h1,h2) : (512, 256) f32.
// dists[i,j] = max(sq[i]+sq[j]-2*dot(b_i,b_j), 1e-7)
// mask nonzero only at k = j^256: t(i,j) = relu(dists[i,j] - dists[i,j^256] + 1)
// outputs (5 x f32): loss, mean(differences)=0 (exact cancellation), good, bad, sqrt(mean(sq))
//
// One kernel: 256 blocks x 512 threads; block b owns rows i0=2b, i1=2b+1.
// sq computed inline (no separate pass); last block finalizes (threadfence +
// atomic counter pattern; counter zeroed each launch by captured memsetAsync).

#define D4 64   // 256 floats / 4

__device__ __forceinline__ const float* batch_row(const float* __restrict__ h1,
                                                  const float* __restrict__ h2,
                                                  int r) {
    return (r < 256) ? (h1 + (size_t)r * 256) : (h2 + (size_t)(r - 256) * 256);
}

__global__ __launch_bounds__(512) void triplet_fused(const float* __restrict__ h1,
                                                     const float* __restrict__ h2,
                                                     float* __restrict__ partials,   // 256 x float4
                                                     unsigned int* __restrict__ counter,
                                                     float* __restrict__ out) {
    const int b = blockIdx.x;    // 0..255
    const int t = threadIdx.x;   // 0..511

    __shared__ float4 arow[2][D4];   // rows i0, i1 staged
    __shared__ float  lds_sq[2];     // sq(i0), sq(i1)
    __shared__ float  drow[2][512];  // dists rows for pair exchange
    __shared__ float  red[4][8];
    __shared__ int    isLast;

    // --- stage the two A-rows; wave0/wave1 also reduce their own sq ---
    if (t < 128) {
        const int r = (t < 64) ? 2 * b : 2 * b + 1;
        const int k = t & 63;
        float4 v = reinterpret_cast<const float4*>(batch_row(h1, h2, r))[k];
        arow[t >> 6][k] = v;
        float s = v.x * v.x + v.y * v.y + v.z * v.z + v.w * v.w;
#pragma unroll
        for (int off = 32; off > 0; off >>= 1) s += __shfl_down(s, off);
        if (k == 0) lds_sq[t >> 6] = s;
    }
    __syncthreads();

    // --- thread t handles column j = t: dot(a0,bj), dot(a1,bj), dot(bj,bj) ---
    const float4* __restrict__ rj = reinterpret_cast<const float4*>(batch_row(h1, h2, t));
    float4 c0 = make_float4(0.f, 0.f, 0.f, 0.f);
    float4 c1 = make_float4(0.f, 0.f, 0.f, 0.f);
    float4 cb = make_float4(0.f, 0.f, 0.f, 0.f);
#pragma unroll 8
    for (int k = 0; k < D4; ++k) {
        float4 bv = rj[k];
        float4 a0 = arow[0][k];
        float4 a1 = arow[1][k];
        c0.x = fmaf(a0.x, bv.x, c0.x); c0.y = fmaf(a0.y, bv.y, c0.y);
        c0.z = fmaf(a0.z, bv.z, c0.z); c0.w = fmaf(a0.w, bv.w, c0.w);
        c1.x = fmaf(a1.x, bv.x, c1.x); c1.y = fmaf(a1.y, bv.y, c1.y);
        c1.z = fmaf(a1.z, bv.z, c1.z); c1.w = fmaf(a1.w, bv.w, c1.w);
        cb.x = fmaf(bv.x, bv.x, cb.x); cb.y = fmaf(bv.y, bv.y, cb.y);
        cb.z = fmaf(bv.z, bv.z, cb.z); cb.w = fmaf(bv.w, bv.w, cb.w);
    }
    const float dot0 = (c0.x + c0.y) + (c0.z + c0.w);
    const float dot1 = (c1.x + c1.y) + (c1.z + c1.w);
    const float sqj  = (cb.x + cb.y) + (cb.z + cb.w);
    const float d0 = fmaxf(lds_sq[0] + sqj - 2.f * dot0, 1e-7f);
    const float d1 = fmaxf(lds_sq[1] + sqj - 2.f * dot1, 1e-7f);
    drow[0][t] = d0;
    drow[1][t] = d1;
    __syncthreads();

    // --- masked triplet entries: (i, j=t) uses pair k = t^256 ---
    const int p = t ^ 256;
    const float t0 = fmaxf(d0 - drow[0][p] + 1.0f, 0.f);
    const float t1 = fmaxf(d1 - drow[1][p] + 1.0f, 0.f);
    float srel = (t0 > 1e-5f ? t0 : 0.f) + (t1 > 1e-5f ? t1 : 0.f);
    float crel = (float)((t0 > 1e-5f) + (t1 > 1e-5f));
    float good = (float)((t0 < 1e-5f) + (t1 < 1e-5f));

#pragma unroll
    for (int off = 32; off > 0; off >>= 1) {
        srel += __shfl_down(srel, off);
        crel += __shfl_down(crel, off);
        good += __shfl_down(good, off);
    }
    const int w = t >> 6;
    if ((t & 63) == 0) { red[0][w] = srel; red[1][w] = crel; red[2][w] = good; }
    __syncthreads();
    if (t == 0) {
        float s = 0.f, c = 0.f, g = 0.f;
#pragma unroll
        for (int q = 0; q < 8; ++q) { s += red[0][q]; c += red[1][q]; g += red[2][q]; }
        float4 pv = make_float4(s, c, g, lds_sq[0] + lds_sq[1]);
        reinterpret_cast<float4*>(partials)[b] = pv;
    }
    __threadfence();                       // release: make partials visible device-wide
    if (t == 0) {
        unsigned int old = atomicAdd(counter, 1u);
        isLast = (old == 255u);
    }
    __syncthreads();
    if (!isLast) return;

    // --- last block: deterministic final reduction over 256 partials ---
    __threadfence();                       // acquire: invalidate stale cache lines
    float4 pv = make_float4(0.f, 0.f, 0.f, 0.f);
    if (t < 256) pv = reinterpret_cast<const float4*>(partials)[t];
    float s = pv.x, c = pv.y, g = pv.z, q = pv.w;
#pragma unroll
    for (int off = 32; off > 0; off >>= 1) {
        s += __shfl_down(s, off);
        c += __shfl_down(c, off);
        g += __shfl_down(g, off);
        q += __shfl_down(q, off);
    }
    if ((t & 63) == 0) { red[0][w] = s; red[1][w] = c; red[2][w] = g; red[3][w] = q; }
    __syncthreads();
    if (t == 0) {
        float ss = 0.f, cc = 0.f, gg = 0.f, qq = 0.f;
#pragma unroll
        for (int k = 0; k < 8; ++k) { ss += red[0][k]; cc += red[1][k]; gg += red[2][k]; qq += red[3][k]; }
        const float mean_sq  = qq / 512.0f;
        const float mean_rel = ss / cc;
        const float goodTot  = 133955584.0f + gg;   // (512^3 - 512^2) + good_masked
        out[0] = mean_rel + 1e-4f * mean_sq;        // loss
        out[1] = 0.0f;                              // mean(differences): exact row cancellation
        out[2] = goodTot;                           // good
        out[3] = 134217728.0f - goodTot;            // bad = 512^3 - good
        out[4] = sqrtf(mean_sq);                    // sqrt(mean norm^2)
    }
}

extern "C" void kernel_launch(void* const* d_in, const int* in_sizes, int n_in,
                              void* d_out, int out_size, void* d_ws, size_t ws_size,
                              hipStream_t stream) {
    (void)in_sizes; (void)n_in; (void)out_size; (void)ws_size;
    const float* h1 = (const float*)d_in[0];
    const float* h2 = (const float*)d_in[1];
    // d_in[2] (h3) is unused by the reference forward.
    float*        partials = (float*)d_ws;                         // 256 * 4 floats = 4 KB
    unsigned int* counter  = (unsigned int*)((char*)d_ws + 4096);  // 4 bytes
    float*        out      = (float*)d_out;

    hipMemsetAsync(counter, 0, sizeof(unsigned int), stream);      // graph-capturable memset node
    triplet_fused<<<256, 512, 0, stream>>>(h1, h2, partials, counter, out);
}

// Round 3
// 55.936 us; speedup vs baseline: 1.1129x; 1.1129x over previous
//
#include <hip/hip_runtime.h>
#include <math.h>

// BatchAllTripletLoss, tiled-Gram formulation.
// batch = concat(h1,h2) : (512, 256) f32.
// G[i][j] = dot(b_i, b_j);  sq[i] = G[i][i]
// dists[i,j] = max(sq[i]+sq[j]-2*G[i][j], 1e-7)
// mask nonzero only at k=j^256:  t(i,j) = relu(dists[i,j]-dists[i,j^256]+1)
// outputs (5 x f32): loss, mean(differences)=0 (exact cancellation), good, bad, sqrt(mean(sq))

#define STRIDE 260   // padded LDS row stride in floats: 16B-aligned, bank-staggered

__device__ __forceinline__ const float* batch_row(const float* __restrict__ h1,
                                                  const float* __restrict__ h2,
                                                  int r) {
    return (r < 256) ? (h1 + (size_t)r * 256) : (h2 + (size_t)(r - 256) * 256);
}

// XOR-swizzled word index for float4 slot c4 of row: spreads same-k4 reads of
// even rows across distinct bank quads (2-way max => free per m136).
__device__ __forceinline__ int lds_word(int row, int c4) {
    return row * STRIDE + 4 * (c4 ^ ((row >> 1) & 15));
}

__device__ __forceinline__ float hsum4(float4 v) { return (v.x + v.y) + (v.z + v.w); }

// --- K1: Gram matrix, 32x32 tiles, 2x2 micro-tile ------------------------
__global__ __launch_bounds__(256) void gram_kernel(const float* __restrict__ h1,
                                                   const float* __restrict__ h2,
                                                   float* __restrict__ G,
                                                   float* __restrict__ sq) {
    const int ib = blockIdx.x >> 4;   // 0..15
    const int jb = blockIdx.x & 15;   // 0..15
    const int t  = threadIdx.x;       // 0..255

    __shared__ __align__(16) float Af[32 * STRIDE];
    __shared__ __align__(16) float Bf[32 * STRIDE];

    // stage both 32-row tiles (32 rows x 64 float4), coalesced, swizzled
#pragma unroll
    for (int p = 0; p < 8; ++p) {
        const int idx = p * 256 + t;
        const int row = idx >> 6, c4 = idx & 63;
        float4 av = reinterpret_cast<const float4*>(batch_row(h1, h2, ib * 32 + row))[c4];
        float4 bv = reinterpret_cast<const float4*>(batch_row(h1, h2, jb * 32 + row))[c4];
        *reinterpret_cast<float4*>(&Af[lds_word(row, c4)]) = av;
        *reinterpret_cast<float4*>(&Bf[lds_word(row, c4)]) = bv;
    }
    __syncthreads();

    const int ty = t >> 4;            // 0..15 -> rows 2ty,2ty+1
    const int tx = t & 15;            // 0..15 -> cols 2tx,2tx+1
    float4 c00 = make_float4(0.f,0.f,0.f,0.f), c01 = c00, c10 = c00, c11 = c00;

#pragma unroll 8
    for (int k4 = 0; k4 < 64; ++k4) {
        const float4 a0 = *reinterpret_cast<const float4*>(&Af[lds_word(2 * ty,     k4)]);
        const float4 a1 = *reinterpret_cast<const float4*>(&Af[lds_word(2 * ty + 1, k4)]);
        const float4 b0 = *reinterpret_cast<const float4*>(&Bf[lds_word(2 * tx,     k4)]);
        const float4 b1 = *reinterpret_cast<const float4*>(&Bf[lds_word(2 * tx + 1, k4)]);
        c00.x = fmaf(a0.x, b0.x, c00.x); c00.y = fmaf(a0.y, b0.y, c00.y);
        c00.z = fmaf(a0.z, b0.z, c00.z); c00.w = fmaf(a0.w, b0.w, c00.w);
        c01.x = fmaf(a0.x, b1.x, c01.x); c01.y = fmaf(a0.y, b1.y, c01.y);
        c01.z = fmaf(a0.z, b1.z, c01.z); c01.w = fmaf(a0.w, b1.w, c01.w);
        c10.x = fmaf(a1.x, b0.x, c10.x); c10.y = fmaf(a1.y, b0.y, c10.y);
        c10.z = fmaf(a1.z, b0.z, c10.z); c10.w = fmaf(a1.w, b0.w, c10.w);
        c11.x = fmaf(a1.x, b1.x, c11.x); c11.y = fmaf(a1.y, b1.y, c11.y);
        c11.z = fmaf(a1.z, b1.z, c11.z); c11.w = fmaf(a1.w, b1.w, c11.w);
    }
    const float s00 = hsum4(c00), s01 = hsum4(c01);
    const float s10 = hsum4(c10), s11 = hsum4(c11);

    const int gi = ib * 32 + 2 * ty;
    const int gj = jb * 32 + 2 * tx;
    *reinterpret_cast<float2*>(&G[(size_t)gi * 512 + gj])       = make_float2(s00, s01);
    *reinterpret_cast<float2*>(&G[(size_t)(gi + 1) * 512 + gj]) = make_float2(s10, s11);
    if (ib == jb && tx == ty) {       // diagonal: sq[i] = G[i][i], for free
        sq[gi]     = s00;
        sq[gi + 1] = s11;
    }
}

// --- K2: pair stats + last-block finalize ---------------------------------
__global__ __launch_bounds__(512) void stats_kernel(const float* __restrict__ G,
                                                    const float* __restrict__ sq,
                                                    float* __restrict__ partials,  // 256 x float4
                                                    unsigned int* __restrict__ counter,
                                                    float* __restrict__ out) {
    const int b = blockIdx.x;    // 0..255 -> rows 2b, 2b+1
    const int t = threadIdx.x;   // 0..511 -> column j = t
    const int tp = t ^ 256;      // paired column
    __shared__ float red[4][8];
    __shared__ int isLast;

    const float sqt = sq[t];
    const float sqp = sq[tp];
    float srel = 0.f, crel = 0.f, good = 0.f;
#pragma unroll
    for (int h = 0; h < 2; ++h) {
        const int i = 2 * b + h;
        const float sqi = sq[i];
        const float d  = fmaxf(sqi + sqt - 2.f * G[(size_t)i * 512 + t],  1e-7f);
        const float dp = fmaxf(sqi + sqp - 2.f * G[(size_t)i * 512 + tp], 1e-7f);
        const float tv = fmaxf(d - dp + 1.0f, 0.f);
        srel += (tv > 1e-5f) ? tv : 0.f;
        crel += (tv > 1e-5f) ? 1.f : 0.f;
        good += (tv < 1e-5f) ? 1.f : 0.f;
    }
#pragma unroll
    for (int off = 32; off > 0; off >>= 1) {
        srel += __shfl_down(srel, off);
        crel += __shfl_down(crel, off);
        good += __shfl_down(good, off);
    }
    const int w = t >> 6;
    if ((t & 63) == 0) { red[0][w] = srel; red[1][w] = crel; red[2][w] = good; }
    __syncthreads();
    if (t == 0) {
        float s = 0.f, c = 0.f, g = 0.f;
#pragma unroll
        for (int q = 0; q < 8; ++q) { s += red[0][q]; c += red[1][q]; g += red[2][q]; }
        reinterpret_cast<float4*>(partials)[b] = make_float4(s, c, g, 0.f);
    }
    __threadfence();                  // release partials
    if (t == 0) {
        unsigned int old = atomicAdd(counter, 1u);
        isLast = (old == 255u);
    }
    __syncthreads();
    if (!isLast) return;

    // last block: deterministic final reduction
    __threadfence();                  // acquire
    float4 pv = make_float4(0.f, 0.f, 0.f, 0.f);
    if (t < 256) pv = reinterpret_cast<const float4*>(partials)[t];
    float s = pv.x, c = pv.y, g = pv.z, q = sq[t];
#pragma unroll
    for (int off = 32; off > 0; off >>= 1) {
        s += __shfl_down(s, off);
        c += __shfl_down(c, off);
        g += __shfl_down(g, off);
        q += __shfl_down(q, off);
    }
    __syncthreads();                  // red[] reuse
    if ((t & 63) == 0) { red[0][w] = s; red[1][w] = c; red[2][w] = g; red[3][w] = q; }
    __syncthreads();
    if (t == 0) {
        float ss = 0.f, cc = 0.f, gg = 0.f, qq = 0.f;
#pragma unroll
        for (int k = 0; k < 8; ++k) { ss += red[0][k]; cc += red[1][k]; gg += red[2][k]; qq += red[3][k]; }
        const float mean_sq  = qq / 512.0f;
        const float mean_rel = ss / cc;
        const float goodTot  = 133955584.0f + gg;   // (512^3 - 512^2) + good_masked
        out[0] = mean_rel + 1e-4f * mean_sq;        // loss
        out[1] = 0.0f;                              // mean(differences): exact cancellation
        out[2] = goodTot;                           // good
        out[3] = 134217728.0f - goodTot;            // bad
        out[4] = sqrtf(mean_sq);                    // sqrt(mean norm^2)
    }
}

extern "C" void kernel_launch(void* const* d_in, const int* in_sizes, int n_in,
                              void* d_out, int out_size, void* d_ws, size_t ws_size,
                              hipStream_t stream) {
    (void)in_sizes; (void)n_in; (void)out_size; (void)ws_size;
    const float* h1 = (const float*)d_in[0];
    const float* h2 = (const float*)d_in[1];
    // d_in[2] (h3) unused by the reference forward.
    char* ws = (char*)d_ws;
    float*        G        = (float*)ws;                    // 512*512*4B = 1 MB
    float*        sq       = (float*)(ws + (1 << 20));      // 512 floats
    float*        partials = (float*)(ws + (1 << 20) + 4096);        // 256 x float4
    unsigned int* counter  = (unsigned int*)(ws + (1 << 20) + 16384);
    float*        out      = (float*)d_out;

    hipMemsetAsync(counter, 0, sizeof(unsigned int), stream);
    gram_kernel <<<256, 256, 0, stream>>>(h1, h2, G, sq);
    stats_kernel<<<256, 512, 0, stream>>>(G, sq, partials, counter, out);
}

// Round 4
// 16.532 us; speedup vs baseline: 3.7655x; 3.3835x over previous
//
#include <hip/hip_runtime.h>
#include <math.h>

// BatchAllTripletLoss, tiled-Gram formulation, fence-free 3-kernel pipeline.
// batch = concat(h1,h2) : (512, 256) f32.
// G[i][j] = dot(b_i, b_j);  sq[i] = G[i][i]
// dists[i,j] = max(sq[i]+sq[j]-2*G[i][j], 1e-7)
// mask nonzero only at k=j^256:  t(i,j) = relu(dists[i,j]-dists[i,j^256]+1)
// outputs (5 x f32): loss, mean(differences)=0 (exact cancellation), good, bad, sqrt(mean(sq))
//
// Round-3 lesson: __threadfence()+atomic last-block finalize cost ~40us on
// gfx950 (device-scope fence = L2 writeback on non-coherent XCD L2s). Use a
// separate 1-block finalize kernel instead; kernel boundary provides ordering.

#define STRIDE 260   // padded LDS row stride in floats: 16B-aligned, bank-staggered

__device__ __forceinline__ const float* batch_row(const float* __restrict__ h1,
                                                  const float* __restrict__ h2,
                                                  int r) {
    return (r < 256) ? (h1 + (size_t)r * 256) : (h2 + (size_t)(r - 256) * 256);
}

// XOR-swizzled word index for float4 slot c4 of row.
__device__ __forceinline__ int lds_word(int row, int c4) {
    return row * STRIDE + 4 * (c4 ^ ((row >> 1) & 15));
}

__device__ __forceinline__ float hsum4(float4 v) { return (v.x + v.y) + (v.z + v.w); }

// --- K1: Gram matrix, 32x32 tiles, 2x2 micro-tile (proven in round 3) -----
__global__ __launch_bounds__(256) void gram_kernel(const float* __restrict__ h1,
                                                   const float* __restrict__ h2,
                                                   float* __restrict__ G,
                                                   float* __restrict__ sq) {
    const int ib = blockIdx.x >> 4;   // 0..15
    const int jb = blockIdx.x & 15;   // 0..15
    const int t  = threadIdx.x;       // 0..255

    __shared__ __align__(16) float Af[32 * STRIDE];
    __shared__ __align__(16) float Bf[32 * STRIDE];

#pragma unroll
    for (int p = 0; p < 8; ++p) {
        const int idx = p * 256 + t;
        const int row = idx >> 6, c4 = idx & 63;
        float4 av = reinterpret_cast<const float4*>(batch_row(h1, h2, ib * 32 + row))[c4];
        float4 bv = reinterpret_cast<const float4*>(batch_row(h1, h2, jb * 32 + row))[c4];
        *reinterpret_cast<float4*>(&Af[lds_word(row, c4)]) = av;
        *reinterpret_cast<float4*>(&Bf[lds_word(row, c4)]) = bv;
    }
    __syncthreads();

    const int ty = t >> 4;            // 0..15 -> rows 2ty,2ty+1
    const int tx = t & 15;            // 0..15 -> cols 2tx,2tx+1
    float4 c00 = make_float4(0.f,0.f,0.f,0.f), c01 = c00, c10 = c00, c11 = c00;

#pragma unroll 8
    for (int k4 = 0; k4 < 64; ++k4) {
        const float4 a0 = *reinterpret_cast<const float4*>(&Af[lds_word(2 * ty,     k4)]);
        const float4 a1 = *reinterpret_cast<const float4*>(&Af[lds_word(2 * ty + 1, k4)]);
        const float4 b0 = *reinterpret_cast<const float4*>(&Bf[lds_word(2 * tx,     k4)]);
        const float4 b1 = *reinterpret_cast<const float4*>(&Bf[lds_word(2 * tx + 1, k4)]);
        c00.x = fmaf(a0.x, b0.x, c00.x); c00.y = fmaf(a0.y, b0.y, c00.y);
        c00.z = fmaf(a0.z, b0.z, c00.z); c00.w = fmaf(a0.w, b0.w, c00.w);
        c01.x = fmaf(a0.x, b1.x, c01.x); c01.y = fmaf(a0.y, b1.y, c01.y);
        c01.z = fmaf(a0.z, b1.z, c01.z); c01.w = fmaf(a0.w, b1.w, c01.w);
        c10.x = fmaf(a1.x, b0.x, c10.x); c10.y = fmaf(a1.y, b0.y, c10.y);
        c10.z = fmaf(a1.z, b0.z, c10.z); c10.w = fmaf(a1.w, b0.w, c10.w);
        c11.x = fmaf(a1.x, b1.x, c11.x); c11.y = fmaf(a1.y, b1.y, c11.y);
        c11.z = fmaf(a1.z, b1.z, c11.z); c11.w = fmaf(a1.w, b1.w, c11.w);
    }
    const float s00 = hsum4(c00), s01 = hsum4(c01);
    const float s10 = hsum4(c10), s11 = hsum4(c11);

    const int gi = ib * 32 + 2 * ty;
    const int gj = jb * 32 + 2 * tx;
    *reinterpret_cast<float2*>(&G[(size_t)gi * 512 + gj])       = make_float2(s00, s01);
    *reinterpret_cast<float2*>(&G[(size_t)(gi + 1) * 512 + gj]) = make_float2(s10, s11);
    if (ib == jb && tx == ty) {       // diagonal: sq[i] = G[i][i], for free
        sq[gi]     = s00;
        sq[gi + 1] = s11;
    }
}

// --- K2: pair stats -> per-block partials (pure, no fences/atomics) -------
__global__ __launch_bounds__(512) void stats_kernel(const float* __restrict__ G,
                                                    const float* __restrict__ sq,
                                                    float* __restrict__ partials) { // 256 x float4
    const int b = blockIdx.x;    // 0..255 -> rows 2b, 2b+1
    const int t = threadIdx.x;   // 0..511 -> column j = t
    const int tp = t ^ 256;      // paired column
    __shared__ float red[3][8];

    const float sqt = sq[t];
    const float sqp = sq[tp];
    float srel = 0.f, crel = 0.f, good = 0.f;
#pragma unroll
    for (int h = 0; h < 2; ++h) {
        const int i = 2 * b + h;
        const float sqi = sq[i];
        const float d  = fmaxf(sqi + sqt - 2.f * G[(size_t)i * 512 + t],  1e-7f);
        const float dp = fmaxf(sqi + sqp - 2.f * G[(size_t)i * 512 + tp], 1e-7f);
        const float tv = fmaxf(d - dp + 1.0f, 0.f);
        srel += (tv > 1e-5f) ? tv : 0.f;
        crel += (tv > 1e-5f) ? 1.f : 0.f;
        good += (tv < 1e-5f) ? 1.f : 0.f;
    }
#pragma unroll
    for (int off = 32; off > 0; off >>= 1) {
        srel += __shfl_down(srel, off);
        crel += __shfl_down(crel, off);
        good += __shfl_down(good, off);
    }
    const int w = t >> 6;
    if ((t & 63) == 0) { red[0][w] = srel; red[1][w] = crel; red[2][w] = good; }
    __syncthreads();
    if (t == 0) {
        float s = 0.f, c = 0.f, g = 0.f;
#pragma unroll
        for (int q = 0; q < 8; ++q) { s += red[0][q]; c += red[1][q]; g += red[2][q]; }
        reinterpret_cast<float4*>(partials)[b] = make_float4(s, c, g, 0.f);
    }
}

// --- K3: final reduction + all 5 outputs ----------------------------------
__global__ __launch_bounds__(512) void finalize_kernel(const float* __restrict__ sq,
                                                       const float* __restrict__ partials,
                                                       float* __restrict__ out) {
    const int t = threadIdx.x;   // 0..511
    float4 pv = make_float4(0.f, 0.f, 0.f, 0.f);
    if (t < 256) pv = reinterpret_cast<const float4*>(partials)[t];
    float s = pv.x, c = pv.y, g = pv.z, q = sq[t];
#pragma unroll
    for (int off = 32; off > 0; off >>= 1) {
        s += __shfl_down(s, off);
        c += __shfl_down(c, off);
        g += __shfl_down(g, off);
        q += __shfl_down(q, off);
    }
    __shared__ float red[4][8];
    const int w = t >> 6;
    if ((t & 63) == 0) { red[0][w] = s; red[1][w] = c; red[2][w] = g; red[3][w] = q; }
    __syncthreads();
    if (t == 0) {
        float ss = 0.f, cc = 0.f, gg = 0.f, qq = 0.f;
#pragma unroll
        for (int k = 0; k < 8; ++k) { ss += red[0][k]; cc += red[1][k]; gg += red[2][k]; qq += red[3][k]; }
        const float mean_sq  = qq / 512.0f;
        const float mean_rel = ss / cc;
        const float goodTot  = 133955584.0f + gg;   // (512^3 - 512^2) + good_masked
        out[0] = mean_rel + 1e-4f * mean_sq;        // loss
        out[1] = 0.0f;                              // mean(differences): exact cancellation
        out[2] = goodTot;                           // good
        out[3] = 134217728.0f - goodTot;            // bad
        out[4] = sqrtf(mean_sq);                    // sqrt(mean norm^2)
    }
}

extern "C" void kernel_launch(void* const* d_in, const int* in_sizes, int n_in,
                              void* d_out, int out_size, void* d_ws, size_t ws_size,
                              hipStream_t stream) {
    (void)in_sizes; (void)n_in; (void)out_size; (void)ws_size;
    const float* h1 = (const float*)d_in[0];
    const float* h2 = (const float*)d_in[1];
    // d_in[2] (h3) unused by the reference forward.
    char* ws = (char*)d_ws;
    float* G        = (float*)ws;                        // 512*512*4B = 1 MB
    float* sq       = (float*)(ws + (1 << 20));          // 512 floats
    float* partials = (float*)(ws + (1 << 20) + 4096);   // 256 x float4
    float* out      = (float*)d_out;

    gram_kernel    <<<256, 256, 0, stream>>>(h1, h2, G, sq);
    stats_kernel   <<<256, 512, 0, stream>>>(G, sq, partials);
    finalize_kernel<<<1,   512, 0, stream>>>(sq, partials, out);
}